// Round 3
// baseline (53339.551 us; speedup 1.0000x reference)
//
#include <hip/hip_runtime.h>

#define S 1024
#define NOBS 4096
#define TSTEPS 8192
#define NWG 64
#define COLS 16   // output columns per WG
#define NTHR 512  // 8 waves
#define NWAVE 8

#define AGENT __HIP_MEMORY_SCOPE_AGENT

typedef __attribute__((ext_vector_type(4))) _Float16 half4;

__device__ __forceinline__ float wmaxred(float v) {
#pragma unroll
  for (int off = 32; off > 0; off >>= 1) v = fmaxf(v, __shfl_xor(v, off, 64));
  return v;
}
__device__ __forceinline__ float wsumred(float v) {
#pragma unroll
  for (int off = 32; off > 0; off >>= 1) v += __shfl_xor(v, off, 64);
  return v;
}

// One-time: Et[j][i] = exp(trans[i][j])  (transposed, fp16) via LDS tile transpose.
__global__ void prep_E(const float* __restrict__ trans, _Float16* __restrict__ Et) {
  __shared__ float tile[32][33];
  const int tx = threadIdx.x, ty = threadIdx.y;
  const int bi = blockIdx.y, bj = blockIdx.x;
  tile[ty][tx] = trans[(size_t)(bi * 32 + ty) * S + bj * 32 + tx];
  __syncthreads();
  Et[(size_t)(bj * 32 + ty) * S + bi * 32 + tx] = (_Float16)__expf(tile[tx][ty]);
}

// One-time: r0 = start + emit[:, obs[0]], packed {tag=0:hi16, fp16:lo16} into buffer 0.
__global__ void hmm_init(const int* __restrict__ obs, const float* __restrict__ start,
                         const float* __restrict__ emit, unsigned* rbuf) {
  const int tid = threadIdx.x;  // 1024 threads
  const float r = start[tid] + emit[(size_t)tid * NOBS + obs[0]];
  const unsigned short h = __builtin_bit_cast(unsigned short, (_Float16)r);
  __hip_atomic_store(&rbuf[tid], (unsigned)h, __ATOMIC_RELAXED, AGENT);  // tag 0 in hi16
}

// Poll 8 u64 words (16 slots) until every u32 half carries `tag` in its hi16.
__device__ __forceinline__ void poll16(const unsigned long long* s64, unsigned tag,
                                       unsigned long long (&w)[8]) {
  const unsigned long long pat =
      ((unsigned long long)tag << 16) | ((unsigned long long)tag << 48);
  const unsigned long long msk = 0xFFFF0000FFFF0000ULL;
  unsigned pend = 0xFF;
  do {
#pragma unroll
    for (int j = 0; j < 8; ++j)
      if (pend & (1u << j)) w[j] = __hip_atomic_load(&s64[j], __ATOMIC_RELAXED, AGENT);
    unsigned np = 0;
#pragma unroll
    for (int j = 0; j < 8; ++j)
      if ((w[j] & msk) != pat) np |= 1u << j;
    pend = np;
  } while (pend);
}

__device__ __forceinline__ float lo_val(unsigned long long w) {
  return (float)__builtin_bit_cast(_Float16, (unsigned short)(w & 0xFFFF));
}
__device__ __forceinline__ float hi_val(unsigned long long w) {
  return (float)__builtin_bit_cast(_Float16, (unsigned short)((w >> 32) & 0xFFFF));
}

__global__ __launch_bounds__(NTHR) void hmm_main(
    const int* __restrict__ obs, const float* __restrict__ emit,
    const _Float16* __restrict__ Et, unsigned* rbuf, float* __restrict__ out) {
  const int tid = threadIdx.x;
  const int lane = tid & 63;
  const int wave = tid >> 6;
  const int wg = blockIdx.x;
  // XCD swizzle: blocks b and b+8 (same XCD, b%8 heuristic) own adjacent chunks,
  // so each XCD's 8 chunks = 512 B = 4 contiguous cachelines of rbuf.
  const int chunk = (wg & 7) * 8 + (wg >> 3);
  const int c0 = chunk * COLS + wave * 2;  // this wave's two output columns

  // E fragments in registers: lane L owns sources i in [16L, 16L+16).
  float4 er[2][4];
#pragma unroll
  for (int cc = 0; cc < 2; ++cc) {
#pragma unroll
    for (int k = 0; k < 4; ++k) {
      const half4 h = *(const half4*)(Et + (size_t)(c0 + cc) * S + lane * 16 + k * 4);
      er[cc][k] = make_float4((float)h[0], (float)h[1], (float)h[2], (float)h[3]);
    }
  }

  unsigned long long* const b0 = (unsigned long long*)rbuf;          // buffer 0, u64 view
  unsigned long long* const b1 = (unsigned long long*)(rbuf + S);    // buffer 1
  const unsigned long long* src;
  unsigned long long w[8];

  // Preamble: read v0 (tag 0), compute initial m = max(v0) — fresh for t=1.
  poll16(b0 + lane * 8, 0u, w);
  float lm = -1e30f;
#pragma unroll
  for (int j = 0; j < 8; ++j) lm = fmaxf(lm, fmaxf(lo_val(w[j]), hi_val(w[j])));
  float m = wmaxred(lm);

  double c = 0.0;  // accumulated scale offset; identical in every thread
  for (int t = 1; t < TSTEPS; ++t) {
    // emit gather for this step — issued before the poll so latency overlaps it
    float e0 = 0.f, e1 = 0.f;
    if (lane == 0) {
      const int ot = obs[t];
      e0 = emit[(size_t)c0 * NOBS + ot];
      e1 = emit[(size_t)(c0 + 1) * NOBS + ot];
    }
    const int tm1 = t - 1;
    src = ((tm1 & 1) ? b1 : b0) + lane * 8;
    poll16(src, (unsigned)tm1, w);

    // unpack, track local max (for next step's stale m), exp, dot
    float nlm = -1e30f;
    float acc0 = 0.f, acc1 = 0.f;
#pragma unroll
    for (int k = 0; k < 4; ++k) {
      const float va = lo_val(w[2 * k]), vb = hi_val(w[2 * k]);
      const float vc = lo_val(w[2 * k + 1]), vd = hi_val(w[2 * k + 1]);
      nlm = fmaxf(nlm, fmaxf(fmaxf(va, vb), fmaxf(vc, vd)));
      const float pa = __expf(va - m), pb = __expf(vb - m);
      const float pc = __expf(vc - m), pd = __expf(vd - m);
      acc0 += pa * er[0][k].x + pb * er[0][k].y + pc * er[0][k].z + pd * er[0][k].w;
      acc1 += pa * er[1][k].x + pb * er[1][k].y + pc * er[1][k].z + pd * er[1][k].w;
    }
    acc0 = wsumred(acc0);
    acc1 = wsumred(acc1);
    c += (double)m;

    // publish both columns as one u64 {slot c0: lo32, slot c0+1: hi32}
    if (lane == 0) {
      const unsigned tg = (unsigned)t << 16;
      const unsigned w0 = tg | __builtin_bit_cast(unsigned short, (_Float16)(__logf(acc0) + e0));
      const unsigned w1 = tg | __builtin_bit_cast(unsigned short, (_Float16)(__logf(acc1) + e1));
      unsigned long long* dst = ((t & 1) ? b1 : b0) + (c0 >> 1);
      __hip_atomic_store(dst, ((unsigned long long)w1 << 32) | w0, __ATOMIC_RELAXED, AGENT);
    }

    // next step's stale m (off the publish critical path)
    m = wmaxred(nlm);
  }

  // Final logsumexp over v_{T-1} by WG 0, wave 0 (its lanes cover all 1024 slots).
  if (wg == 0 && wave == 0) {
    const int tf = TSTEPS - 1;
    src = ((tf & 1) ? b1 : b0) + lane * 8;
    poll16(src, (unsigned)tf, w);
    float v[16];
#pragma unroll
    for (int k = 0; k < 8; ++k) { v[2 * k] = lo_val(w[k]); v[2 * k + 1] = hi_val(w[k]); }
    float g = -1e30f;
#pragma unroll
    for (int j = 0; j < 16; ++j) g = fmaxf(g, v[j]);
    g = wmaxred(g);
    float s = 0.f;
#pragma unroll
    for (int j = 0; j < 16; ++j) s += __expf(v[j] - g);
    s = wsumred(s);
    if (lane == 0) out[0] = (float)(c + (double)g + (double)__logf(s));
  }
}

extern "C" void kernel_launch(void* const* d_in, const int* in_sizes, int n_in,
                              void* d_out, int out_size, void* d_ws, size_t ws_size,
                              hipStream_t stream) {
  const int* obs = (const int*)d_in[0];
  const float* start = (const float*)d_in[1];
  const float* trans = (const float*)d_in[2];
  const float* emit = (const float*)d_in[3];

  // ws layout: 0: rbuf[2][1024] u32 (8 KB) | 16384: Et 1024*1024 fp16 (2 MB)
  unsigned* rbuf = (unsigned*)d_ws;
  _Float16* Et = (_Float16*)((char*)d_ws + 16384);

  prep_E<<<dim3(32, 32), dim3(32, 32), 0, stream>>>(trans, Et);
  hmm_init<<<1, S, 0, stream>>>(obs, start, emit, rbuf);
  hmm_main<<<NWG, NTHR, 0, stream>>>(obs, emit, Et, rbuf, (float*)d_out);
}

// Round 4
// 12594.671 us; speedup vs baseline: 4.2351x; 4.2351x over previous
//
#include <hip/hip_runtime.h>

#define S 1024
#define NOBS 4096
#define TSTEPS 8192
#define NWG 64
#define COLS 16   // output columns per WG
#define NTHR 512  // 8 waves
#define NWAVE 8

#define AGENT __HIP_MEMORY_SCOPE_AGENT

typedef __attribute__((ext_vector_type(4))) _Float16 half4;

__device__ __forceinline__ float wmaxred(float v) {
#pragma unroll
  for (int off = 32; off > 0; off >>= 1) v = fmaxf(v, __shfl_xor(v, off, 64));
  return v;
}
__device__ __forceinline__ float wsumred(float v) {
#pragma unroll
  for (int off = 32; off > 0; off >>= 1) v += __shfl_xor(v, off, 64);
  return v;
}

// One-time: Et[j][i] = exp(trans[i][j])  (transposed, fp16) via LDS tile transpose.
__global__ void prep_E(const float* __restrict__ trans, _Float16* __restrict__ Et) {
  __shared__ float tile[32][33];
  const int tx = threadIdx.x, ty = threadIdx.y;
  const int bi = blockIdx.y, bj = blockIdx.x;
  tile[ty][tx] = trans[(size_t)(bi * 32 + ty) * S + bj * 32 + tx];
  __syncthreads();
  Et[(size_t)(bj * 32 + ty) * S + bi * 32 + tx] = (_Float16)__expf(tile[tx][ty]);
}

// One-time: r0 = start + emit[:, obs[0]], packed {tag=0:hi16, fp16:lo16} into buffer 0.
__global__ void hmm_init(const int* __restrict__ obs, const float* __restrict__ start,
                         const float* __restrict__ emit, unsigned* rbuf) {
  const int tid = threadIdx.x;  // 1024 threads
  const float r = start[tid] + emit[(size_t)tid * NOBS + obs[0]];
  const unsigned short h = __builtin_bit_cast(unsigned short, (_Float16)r);
  __hip_atomic_store(&rbuf[tid], (unsigned)h, __ATOMIC_RELAXED, AGENT);  // tag 0 in hi16
}

__device__ __forceinline__ float lo_val(unsigned long long w) {
  return (float)__builtin_bit_cast(_Float16, (unsigned short)(w & 0xFFFF));
}
__device__ __forceinline__ float hi_val(unsigned long long w) {
  return (float)__builtin_bit_cast(_Float16, (unsigned short)((w >> 32) & 0xFFFF));
}

// Poll one u64 (2 slots) until both hi16 tags == tag. Producer writes this u64
// with a single atomic store, so both halves appear together.
__device__ __forceinline__ unsigned long long poll1(const unsigned long long* a,
                                                    unsigned tag) {
  const unsigned long long pat =
      ((unsigned long long)tag << 16) | ((unsigned long long)tag << 48);
  const unsigned long long msk = 0xFFFF0000FFFF0000ULL;
  unsigned long long w;
  do {
    w = __hip_atomic_load(a, __ATOMIC_RELAXED, AGENT);
  } while ((w & msk) != pat);
  return w;
}

// Poll 8 u64 (16 slots) — used once for the final reduction.
__device__ __forceinline__ void poll16(const unsigned long long* s64, unsigned tag,
                                       unsigned long long (&w)[8]) {
  const unsigned long long pat =
      ((unsigned long long)tag << 16) | ((unsigned long long)tag << 48);
  const unsigned long long msk = 0xFFFF0000FFFF0000ULL;
  unsigned pend = 0xFF;
  do {
#pragma unroll
    for (int j = 0; j < 8; ++j)
      if (pend & (1u << j)) w[j] = __hip_atomic_load(&s64[j], __ATOMIC_RELAXED, AGENT);
    unsigned np = 0;
#pragma unroll
    for (int j = 0; j < 8; ++j)
      if ((w[j] & msk) != pat) np |= 1u << j;
    pend = np;
  } while (pend);
}

__global__ __launch_bounds__(NTHR) void hmm_main(
    const int* __restrict__ obs, const float* __restrict__ emit,
    const _Float16* __restrict__ Et, unsigned* rbuf, float* __restrict__ out) {
  __shared__ float p[2][S];     // double-buffered by step parity (8 KB)
  __shared__ float wred[NWAVE];
  const int tid = threadIdx.x;
  const int lane = tid & 63;
  const int wave = tid >> 6;
  const int wg = blockIdx.x;
  // XCD swizzle: each XCD's 8 WGs own 4 contiguous cachelines of rbuf.
  const int chunk = (wg & 7) * 8 + (wg >> 3);
  const int c0 = chunk * COLS + wave * 2;  // this wave's two output columns

  // E fragments in registers matching the LDS-p dot indexing:
  // er[cc][k] covers sources {256k + 4*lane .. 256k + 4*lane + 3}.
  float4 er[2][4];
#pragma unroll
  for (int cc = 0; cc < 2; ++cc) {
#pragma unroll
    for (int k = 0; k < 4; ++k) {
      const half4 h = *(const half4*)(Et + (size_t)(c0 + cc) * S + k * 256 + lane * 4);
      er[cc][k] = make_float4((float)h[0], (float)h[1], (float)h[2], (float)h[3]);
    }
  }

  unsigned long long* const b0 = (unsigned long long*)rbuf;        // buffer 0 (even t)
  unsigned long long* const b1 = (unsigned long long*)(rbuf + S);  // buffer 1 (odd t)

  // Preamble: poll own u64 of r_0, compute m = max(r_0) (bit-identical in all WGs).
  {
    const unsigned long long w = poll1(b0 + tid, 0u);
    const float lm = fmaxf(lo_val(w), hi_val(w));
    const float wm = wmaxred(lm);
    if (lane == 0) wred[wave] = wm;
  }
  __syncthreads();
  float m = wred[0];
#pragma unroll
  for (int k = 1; k < NWAVE; ++k) m = fmaxf(m, wred[k]);

  double c = 0.0;  // accumulated scale offset; identical in every thread
  for (int t = 1; t < TSTEPS; ++t) {
    // emit gather for this step — issued before the poll so latency overlaps it
    float e0 = 0.f, e1 = 0.f;
    if (lane == 0) {
      const int ot = obs[t];
      e0 = emit[(size_t)c0 * NOBS + ot];
      e1 = emit[(size_t)(c0 + 1) * NOBS + ot];
    }
    // poll the single u64 this thread owns (slots 2tid, 2tid+1 of r_{t-1})
    const unsigned long long* src = ((t & 1) ? b0 : b1) + tid;  // t-1 parity
    const unsigned long long w = poll1(src, (unsigned)(t - 1));
    float* const pb = p[t & 1];
    pb[2 * tid] = __expf(lo_val(w) - m);
    pb[2 * tid + 1] = __expf(hi_val(w) - m);
    __syncthreads();  // the only barrier per step

    // dot over all 1024 p values; track maxp alongside for next step's stale m
    float acc0 = 0.f, acc1 = 0.f, maxp = 0.f;
    const float4* p4 = (const float4*)pb;
#pragma unroll
    for (int k = 0; k < 4; ++k) {
      const float4 pv = p4[k * 64 + lane];
      maxp = fmaxf(maxp, fmaxf(fmaxf(pv.x, pv.y), fmaxf(pv.z, pv.w)));
      acc0 += pv.x * er[0][k].x + pv.y * er[0][k].y + pv.z * er[0][k].z + pv.w * er[0][k].w;
      acc1 += pv.x * er[1][k].x + pv.y * er[1][k].y + pv.z * er[1][k].z + pv.w * er[1][k].w;
    }
    acc0 = wsumred(acc0);
    acc1 = wsumred(acc1);

    // publish both columns as one u64 (slots c0, c0+1 of r_t)
    if (lane == 0) {
      const unsigned tg = (unsigned)t << 16;
      const unsigned w0 = tg | __builtin_bit_cast(unsigned short, (_Float16)(__logf(acc0) + e0));
      const unsigned w1 = tg | __builtin_bit_cast(unsigned short, (_Float16)(__logf(acc1) + e1));
      unsigned long long* dst = ((t & 1) ? b1 : b0) + (c0 >> 1);
      __hip_atomic_store(dst, ((unsigned long long)w1 << 32) | w0, __ATOMIC_RELAXED, AGENT);
    }

    // off the critical path: c update and next step's stale m
    c += (double)m;
    maxp = wmaxred(maxp);            // max over all 1024 p (lane set covers all)
    m = m + __logf(maxp);            // = max(r_{t-1}); identical in every WG
  }

  // Final logsumexp over r_{T-1} by WG 0, wave 0 (lanes cover all 1024 slots).
  if (wg == 0 && wave == 0) {
    const int tf = TSTEPS - 1;
    const unsigned long long* src = ((tf & 1) ? b1 : b0) + lane * 8;
    unsigned long long w[8];
    poll16(src, (unsigned)tf, w);
    float v[16];
#pragma unroll
    for (int k = 0; k < 8; ++k) { v[2 * k] = lo_val(w[k]); v[2 * k + 1] = hi_val(w[k]); }
    float g = -1e30f;
#pragma unroll
    for (int j = 0; j < 16; ++j) g = fmaxf(g, v[j]);
    g = wmaxred(g);
    float s = 0.f;
#pragma unroll
    for (int j = 0; j < 16; ++j) s += __expf(v[j] - g);
    s = wsumred(s);
    if (lane == 0) out[0] = (float)(c + (double)g + (double)__logf(s));
  }
}

extern "C" void kernel_launch(void* const* d_in, const int* in_sizes, int n_in,
                              void* d_out, int out_size, void* d_ws, size_t ws_size,
                              hipStream_t stream) {
  const int* obs = (const int*)d_in[0];
  const float* start = (const float*)d_in[1];
  const float* trans = (const float*)d_in[2];
  const float* emit = (const float*)d_in[3];

  // ws layout: 0: rbuf[2][1024] u32 (8 KB) | 16384: Et 1024*1024 fp16 (2 MB)
  unsigned* rbuf = (unsigned*)d_ws;
  _Float16* Et = (_Float16*)((char*)d_ws + 16384);

  prep_E<<<dim3(32, 32), dim3(32, 32), 0, stream>>>(trans, Et);
  hmm_init<<<1, S, 0, stream>>>(obs, start, emit, rbuf);
  hmm_main<<<NWG, NTHR, 0, stream>>>(obs, emit, Et, rbuf, (float*)d_out);
}